// Round 10
// baseline (103.099 us; speedup 1.0000x reference)
//
#include <hip/hip_runtime.h>

#define LSEQ 4096
#define ROWS 4
#define NB (LSEQ / ROWS)   // 1024 blocks -> 4 blocks/CU
#define NT 256

#define IDEAL 6.0f
#define MIN_DIST 3.4f
#define TARGET 9.0f   // 1.5 * IDEAL
#define W_BOND 1.0f
#define W_CLASH 2.0f
#define W_PAIR 0.5f

// Session rules (hard-won):
// - NO atomics/fences in hot kernel: device-scope fence on gfx950 = per-XCD
//   L2 writeback/invalidate; 2048 of them cost ~100us (R3-R5).
// - NO big indexed per-thread arrays: compiler sinks them into the loop
//   (R4). NAMED slots only.
// - Raw v_sqrt_f32 (__builtin_amdgcn_sqrtf): libm fixup ~1/3 of VALU (R8).
// - R10: ROWS=4 — each block issues its ENTIRE HBM demand (16 cmap float4,
//   named slots) up front; half the latency exposures, 2x MLP per wave.
//
// ws layout: float4 per block: {clash, pair, count, 0}. Count exact in fp32
// (cmap is 0.0/1.0, total ~167k << 2^24).

__global__ __launch_bounds__(NT) void er_pair(
        const float* __restrict__ coords,
        const float* __restrict__ cmap,
        float4* __restrict__ ws) {
    const int t = threadIdx.x;
    const int b = blockIdx.x;
    const int i0 = b * ROWS;

    const float4* cp4 = (const float4*)coords;
    const float4* crow0 = (const float4*)(cmap + (size_t)(i0 + 0) * LSEQ);
    const float4* crow1 = (const float4*)(cmap + (size_t)(i0 + 1) * LSEQ);
    const float4* crow2 = (const float4*)(cmap + (size_t)(i0 + 2) * LSEQ);
    const float4* crow3 = (const float4*)(cmap + (size_t)(i0 + 3) * LSEQ);

    // ---- entire block HBM demand up front: 16 x 16B/lane in flight ----
    float4 M00 = crow0[t +   0], M01 = crow0[t + 256],
           M02 = crow0[t + 512], M03 = crow0[t + 768];
    float4 M10 = crow1[t +   0], M11 = crow1[t + 256],
           M12 = crow1[t + 512], M13 = crow1[t + 768];
    float4 M20 = crow2[t +   0], M21 = crow2[t + 256],
           M22 = crow2[t + 512], M23 = crow2[t + 768];
    float4 M30 = crow3[t +   0], M31 = crow3[t + 256],
           M32 = crow3[t + 512], M33 = crow3[t + 768];

    // coord tile 0 (L1/L2-hot after first blocks)
    float4 A = cp4[3 * t + 0];
    float4 B = cp4[3 * t + 1];
    float4 C = cp4[3 * t + 2];

    // wave-uniform row coords -> scalar loads
    const float xi0 = coords[3 * i0 + 0], yi0 = coords[3 * i0 + 1], zi0 = coords[3 * i0 + 2];
    const float xi1 = coords[3 * i0 + 3], yi1 = coords[3 * i0 + 4], zi1 = coords[3 * i0 + 5];
    const float xi2 = coords[3 * i0 + 6], yi2 = coords[3 * i0 + 7], zi2 = coords[3 * i0 + 8];
    const float xi3 = coords[3 * i0 + 9], yi3 = coords[3 * i0 + 10], zi3 = coords[3 * i0 + 11];

    float cl0 = 0.0f, cl1 = 0.0f, cl2 = 0.0f, cl3 = 0.0f;
    float pr0 = 0.0f, pr1 = 0.0f, pr2 = 0.0f, pr3 = 0.0f;
    float ct0 = 0.0f, ct1 = 0.0f, ct2 = 0.0f, ct3 = 0.0f;

// one row's contribution for lane-pair (q): row r uses sep_r = sep0 - r
#define ROW_TERM(R, XI, YI, ZI, CV, CLACC, PRACC, CTACC)                      \
    do {                                                                      \
        const float dx = XI - xs[q];                                          \
        const float dy = YI - ys[q];                                          \
        const float dz = ZI - zs[q];                                          \
        const float d2 = fmaf(dx, dx, fmaf(dy, dy, dz * dz));                 \
        const float d = __builtin_amdgcn_sqrtf(d2);                           \
        float cl = fmaxf(MIN_DIST - d, 0.0f);                                 \
        cl = (sep0 >= 3 + (R)) ? cl : 0.0f;                                   \
        CLACC = fmaf(cl, cl, CLACC);                                          \
        const float pdm = ((unsigned int)(sep0 - (R) + 2) > 4u)               \
                              ? (d - TARGET) : 0.0f;                          \
        PRACC = fmaf(CV[q] * pdm, pdm, PRACC);                                \
        CTACC += CV[q];                                                       \
    } while (0)

#define COMP_TILE(K, A_, B_, C_, m0, m1, m2, m3)                              \
    do {                                                                      \
        const float xs[4] = {A_.x, A_.w, B_.z, C_.y};                         \
        const float ys[4] = {A_.y, B_.x, B_.w, C_.z};                         \
        const float zs[4] = {A_.z, B_.y, C_.x, C_.w};                         \
        const float cv0[4] = {m0.x, m0.y, m0.z, m0.w};                        \
        const float cv1[4] = {m1.x, m1.y, m1.z, m1.w};                        \
        const float cv2[4] = {m2.x, m2.y, m2.z, m2.w};                        \
        const float cv3[4] = {m3.x, m3.y, m3.z, m3.w};                        \
        const int jbase = 4 * t + 1024 * (K);                                 \
        _Pragma("unroll")                                                     \
        for (int q = 0; q < 4; ++q) {                                         \
            const int sep0 = jbase + q - i0;                                  \
            ROW_TERM(0, xi0, yi0, zi0, cv0, cl0, pr0, ct0);                   \
            ROW_TERM(1, xi1, yi1, zi1, cv1, cl1, pr1, ct1);                   \
            ROW_TERM(2, xi2, yi2, zi2, cv2, cl2, pr2, ct2);                   \
            ROW_TERM(3, xi3, yi3, zi3, cv3, cl3, pr3, ct3);                   \
        }                                                                     \
    } while (0)

    // depth-1 coord pipeline over 4 k-tiles; cmap already resident
    float4 An, Bn, Cn;

    An = cp4[3 * t + 768 + 0]; Bn = cp4[3 * t + 768 + 1]; Cn = cp4[3 * t + 768 + 2];
    COMP_TILE(0, A, B, C, M00, M10, M20, M30);
    A = An; B = Bn; C = Cn;

    An = cp4[3 * t + 1536 + 0]; Bn = cp4[3 * t + 1536 + 1]; Cn = cp4[3 * t + 1536 + 2];
    COMP_TILE(1, A, B, C, M01, M11, M21, M31);
    A = An; B = Bn; C = Cn;

    An = cp4[3 * t + 2304 + 0]; Bn = cp4[3 * t + 2304 + 1]; Cn = cp4[3 * t + 2304 + 2];
    COMP_TILE(2, A, B, C, M02, M12, M22, M32);
    A = An; B = Bn; C = Cn;

    COMP_TILE(3, A, B, C, M03, M13, M23, M33);

#undef COMP_TILE
#undef ROW_TERM

    float clash_acc = (cl0 + cl1) + (cl2 + cl3);
    float pair_acc = (pr0 + pr1) + (pr2 + pr3);
    float cnt_acc = (ct0 + ct1) + (ct2 + ct3);

#pragma unroll
    for (int off = 32; off > 0; off >>= 1) {
        clash_acc += __shfl_down(clash_acc, off);
        pair_acc  += __shfl_down(pair_acc, off);
        cnt_acc   += __shfl_down(cnt_acc, off);
    }
    __shared__ float s_clash[NT / 64], s_pair[NT / 64], s_cnt[NT / 64];
    const int wave = t >> 6;
    const int lane = t & 63;
    if (lane == 0) { s_clash[wave] = clash_acc; s_pair[wave] = pair_acc; s_cnt[wave] = cnt_acc; }
    __syncthreads();
    if (t == 0) {
        float cs = 0.0f, ps = 0.0f, ns = 0.0f;
#pragma unroll
        for (int w = 0; w < NT / 64; ++w) { cs += s_clash[w]; ps += s_pair[w]; ns += s_cnt[w]; }
        ws[b] = make_float4(cs, ps, ns, 0.0f);   // slot write: no atomics/fences
    }
}

__global__ __launch_bounds__(NT) void er_finalize(
        const float* __restrict__ coords,
        const float4* __restrict__ ws,
        float* __restrict__ out) {
    const int t = threadIdx.x;
    float cs = 0.0f, ps = 0.0f, ns = 0.0f;
    for (int idx = t; idx < NB; idx += NT) {
        const float4 v = ws[idx];
        cs += v.x; ps += v.y; ns += v.z;
    }
    // bond term
    float bacc = 0.0f;
    for (int s = t; s < LSEQ - 1; s += NT) {
        const float dx = coords[3 * (s + 1) + 0] - coords[3 * s + 0];
        const float dy = coords[3 * (s + 1) + 1] - coords[3 * s + 1];
        const float dz = coords[3 * (s + 1) + 2] - coords[3 * s + 2];
        const float d = __builtin_amdgcn_sqrtf(fmaf(dx, dx, fmaf(dy, dy, dz * dz)));
        const float e = d - IDEAL;
        bacc += e * e;
    }
#pragma unroll
    for (int off = 32; off > 0; off >>= 1) {
        cs += __shfl_down(cs, off);
        ps += __shfl_down(ps, off);
        ns += __shfl_down(ns, off);
        bacc += __shfl_down(bacc, off);
    }
    __shared__ float sc[NT / 64], sp[NT / 64], sn[NT / 64], sb[NT / 64];
    const int wave = t >> 6;
    const int lane = t & 63;
    if (lane == 0) { sc[wave] = cs; sp[wave] = ps; sn[wave] = ns; sb[wave] = bacc; }
    __syncthreads();
    if (t == 0) {
        float tc = 0.0f, tp = 0.0f, tn = 0.0f, tb = 0.0f;
#pragma unroll
        for (int w = 0; w < NT / 64; ++w) { tc += sc[w]; tp += sp[w]; tn += sn[w]; tb += sb[w]; }
        const float e_bond = tb / (float)(LSEQ - 1);
        const float e_clash = tc / (float)LSEQ;
        const float e_pair = tp / fmaxf(tn, 1.0f);
        out[0] = W_BOND * e_bond + W_CLASH * e_clash + W_PAIR * e_pair;
    }
}

extern "C" void kernel_launch(void* const* d_in, const int* in_sizes, int n_in,
                              void* d_out, int out_size, void* d_ws, size_t ws_size,
                              hipStream_t stream) {
    const float* coords = (const float*)d_in[0];
    const float* cmap   = (const float*)d_in[1];
    float4* ws = (float4*)d_ws;
    float* out = (float*)d_out;

    hipLaunchKernelGGL(er_pair, dim3(NB), dim3(NT), 0, stream, coords, cmap, ws);
    hipLaunchKernelGGL(er_finalize, dim3(1), dim3(NT), 0, stream, coords, ws, out);
}

// Round 11
// 101.341 us; speedup vs baseline: 1.0173x; 1.0173x over previous
//
#include <hip/hip_runtime.h>

#define LSEQ 4096
#define ROWS 2
#define NB (LSEQ / ROWS)   // 2048 blocks
#define NT 256

#define IDEAL 6.0f
#define MIN_DIST 3.4f
#define TARGET 9.0f   // 1.5 * IDEAL
#define W_BOND 1.0f
#define W_CLASH 2.0f
#define W_PAIR 0.5f

// Session rules (hard-won):
// - NO atomics/fences in the hot kernel: device-scope fence on gfx950 =
//   per-XCD L2 writeback/invalidate; 2048 of them cost ~100us (R3-R5).
// - NO big indexed per-thread arrays: compiler sinks them into the loop
//   regardless of __launch_bounds__ (R4). Named slots only.
// - Raw v_sqrt_f32 (__builtin_amdgcn_sqrtf): libm fixup was ~1/3 of VALU (R8).
// - R9 config is the session best (101.5us): ROWS=2, all 8 cmap float4s
//   (the HBM stream) issued up front in named slots, coord loads depth-1.
// - R10 (ROWS=4, 16 upfront slots) was neutral/worse: fewer waves offset
//   the extra per-wave MLP. Reverted.
//
// ws layout: float4 per block slot: {clash, pair, count, 0}. Count is exact
// in fp32 (cmap is 0.0/1.0, total ~167k << 2^24).

__global__ __launch_bounds__(NT) void er_pair(
        const float* __restrict__ coords,
        const float* __restrict__ cmap,
        float4* __restrict__ ws) {
    const int t = threadIdx.x;
    const int b = blockIdx.x;
    const int i0 = b * ROWS, i1 = i0 + 1;

    const float4* cp4 = (const float4*)coords;
    const float4* crow0 = (const float4*)(cmap + (size_t)i0 * LSEQ);
    const float4* crow1 = (const float4*)(cmap + (size_t)i1 * LSEQ);

    // ---- issue ALL cmap loads first: 8 x 16B/lane in flight (HBM stream) ----
    float4 M00 = crow0[t +   0], M01 = crow0[t + 256],
           M02 = crow0[t + 512], M03 = crow0[t + 768];
    float4 M10 = crow1[t +   0], M11 = crow1[t + 256],
           M12 = crow1[t + 512], M13 = crow1[t + 768];

    // coord tile 0 (L1/L2-hot after first blocks)
    float4 A = cp4[3 * t + 0];
    float4 B = cp4[3 * t + 1];
    float4 C = cp4[3 * t + 2];

    // wave-uniform row coords -> scalar loads
    const float xi0 = coords[3 * i0 + 0], yi0 = coords[3 * i0 + 1], zi0 = coords[3 * i0 + 2];
    const float xi1 = coords[3 * i1 + 0], yi1 = coords[3 * i1 + 1], zi1 = coords[3 * i1 + 2];

    float cl0 = 0.0f, cl1 = 0.0f;
    float pr0 = 0.0f, pr1 = 0.0f;
    float ct0 = 0.0f, ct1 = 0.0f;

#define COMP_TILE(K, A_, B_, C_, M0, M1)                                      \
    do {                                                                      \
        const float xs[4] = {A_.x, A_.w, B_.z, C_.y};                         \
        const float ys[4] = {A_.y, B_.x, B_.w, C_.z};                         \
        const float zs[4] = {A_.z, B_.y, C_.x, C_.w};                         \
        const float cv0[4] = {M0.x, M0.y, M0.z, M0.w};                        \
        const float cv1[4] = {M1.x, M1.y, M1.z, M1.w};                        \
        const int jbase = 4 * t + 1024 * (K);                                 \
        _Pragma("unroll")                                                     \
        for (int q = 0; q < 4; ++q) {                                         \
            const int sep0 = jbase + q - i0;  /* sep1 = sep0 - 1 */           \
            {   /* row 0 */                                                   \
                const float dx = xi0 - xs[q];                                 \
                const float dy = yi0 - ys[q];                                 \
                const float dz = zi0 - zs[q];                                 \
                const float d2 = fmaf(dx, dx, fmaf(dy, dy, dz * dz));         \
                const float d = __builtin_amdgcn_sqrtf(d2);                   \
                float cl = fmaxf(MIN_DIST - d, 0.0f);                         \
                cl = (sep0 >= 3) ? cl : 0.0f;                                 \
                cl0 = fmaf(cl, cl, cl0);                                      \
                const float pdm = ((unsigned int)(sep0 + 2) > 4u)             \
                                      ? (d - TARGET) : 0.0f;                  \
                pr0 = fmaf(cv0[q] * pdm, pdm, pr0);                           \
                ct0 += cv0[q];                                                \
            }                                                                 \
            {   /* row 1 */                                                   \
                const float dx = xi1 - xs[q];                                 \
                const float dy = yi1 - ys[q];                                 \
                const float dz = zi1 - zs[q];                                 \
                const float d2 = fmaf(dx, dx, fmaf(dy, dy, dz * dz));         \
                const float d = __builtin_amdgcn_sqrtf(d2);                   \
                float cl = fmaxf(MIN_DIST - d, 0.0f);                         \
                cl = (sep0 >= 4) ? cl : 0.0f;                                 \
                cl1 = fmaf(cl, cl, cl1);                                      \
                const float pdm = ((unsigned int)(sep0 + 1) > 4u)             \
                                      ? (d - TARGET) : 0.0f;                  \
                pr1 = fmaf(cv1[q] * pdm, pdm, pr1);                           \
                ct1 += cv1[q];                                                \
            }                                                                 \
        }                                                                     \
    } while (0)

    // depth-1 coord pipeline over 4 tiles; cmap already resident
    float4 An, Bn, Cn;

    An = cp4[3 * t + 768 + 0]; Bn = cp4[3 * t + 768 + 1]; Cn = cp4[3 * t + 768 + 2];
    COMP_TILE(0, A, B, C, M00, M10);
    A = An; B = Bn; C = Cn;

    An = cp4[3 * t + 1536 + 0]; Bn = cp4[3 * t + 1536 + 1]; Cn = cp4[3 * t + 1536 + 2];
    COMP_TILE(1, A, B, C, M01, M11);
    A = An; B = Bn; C = Cn;

    An = cp4[3 * t + 2304 + 0]; Bn = cp4[3 * t + 2304 + 1]; Cn = cp4[3 * t + 2304 + 2];
    COMP_TILE(2, A, B, C, M02, M12);
    A = An; B = Bn; C = Cn;

    COMP_TILE(3, A, B, C, M03, M13);

#undef COMP_TILE

    float clash_acc = cl0 + cl1;
    float pair_acc = pr0 + pr1;
    float cnt_acc = ct0 + ct1;

#pragma unroll
    for (int off = 32; off > 0; off >>= 1) {
        clash_acc += __shfl_down(clash_acc, off);
        pair_acc  += __shfl_down(pair_acc, off);
        cnt_acc   += __shfl_down(cnt_acc, off);
    }
    __shared__ float s_clash[NT / 64], s_pair[NT / 64], s_cnt[NT / 64];
    const int wave = t >> 6;
    const int lane = t & 63;
    if (lane == 0) { s_clash[wave] = clash_acc; s_pair[wave] = pair_acc; s_cnt[wave] = cnt_acc; }
    __syncthreads();
    if (t == 0) {
        float cs = 0.0f, ps = 0.0f, ns = 0.0f;
#pragma unroll
        for (int w = 0; w < NT / 64; ++w) { cs += s_clash[w]; ps += s_pair[w]; ns += s_cnt[w]; }
        ws[b] = make_float4(cs, ps, ns, 0.0f);   // one slot write: no atomics/fences
    }
}

__global__ __launch_bounds__(NT) void er_finalize(
        const float* __restrict__ coords,
        const float4* __restrict__ ws,
        float* __restrict__ out) {
    const int t = threadIdx.x;
    float cs = 0.0f, ps = 0.0f, ns = 0.0f;
    for (int idx = t; idx < NB; idx += NT) {
        const float4 v = ws[idx];
        cs += v.x; ps += v.y; ns += v.z;
    }
    // bond term
    float bacc = 0.0f;
    for (int s = t; s < LSEQ - 1; s += NT) {
        const float dx = coords[3 * (s + 1) + 0] - coords[3 * s + 0];
        const float dy = coords[3 * (s + 1) + 1] - coords[3 * s + 1];
        const float dz = coords[3 * (s + 1) + 2] - coords[3 * s + 2];
        const float d = __builtin_amdgcn_sqrtf(fmaf(dx, dx, fmaf(dy, dy, dz * dz)));
        const float e = d - IDEAL;
        bacc += e * e;
    }
#pragma unroll
    for (int off = 32; off > 0; off >>= 1) {
        cs += __shfl_down(cs, off);
        ps += __shfl_down(ps, off);
        ns += __shfl_down(ns, off);
        bacc += __shfl_down(bacc, off);
    }
    __shared__ float sc[NT / 64], sp[NT / 64], sn[NT / 64], sb[NT / 64];
    const int wave = t >> 6;
    const int lane = t & 63;
    if (lane == 0) { sc[wave] = cs; sp[wave] = ps; sn[wave] = ns; sb[wave] = bacc; }
    __syncthreads();
    if (t == 0) {
        float tc = 0.0f, tp = 0.0f, tn = 0.0f, tb = 0.0f;
#pragma unroll
        for (int w = 0; w < NT / 64; ++w) { tc += sc[w]; tp += sp[w]; tn += sn[w]; tb += sb[w]; }
        const float e_bond = tb / (float)(LSEQ - 1);
        const float e_clash = tc / (float)LSEQ;
        const float e_pair = tp / fmaxf(tn, 1.0f);
        out[0] = W_BOND * e_bond + W_CLASH * e_clash + W_PAIR * e_pair;
    }
}

extern "C" void kernel_launch(void* const* d_in, const int* in_sizes, int n_in,
                              void* d_out, int out_size, void* d_ws, size_t ws_size,
                              hipStream_t stream) {
    const float* coords = (const float*)d_in[0];
    const float* cmap   = (const float*)d_in[1];
    float4* ws = (float4*)d_ws;
    float* out = (float*)d_out;

    hipLaunchKernelGGL(er_pair, dim3(NB), dim3(NT), 0, stream, coords, cmap, ws);
    hipLaunchKernelGGL(er_finalize, dim3(1), dim3(NT), 0, stream, coords, ws, out);
}